// Round 9
// baseline (1452.660 us; speedup 1.0000x reference)
//
#include <hip/hip_runtime.h>

#define NXY 160
#define NT 12
#define SP 25600
#define SLAB_U16 3276800ull          // one hi or lo slab: 8*SP*16 u16
#define SLOT_U16 6553600ull          // hi+lo pair
#define SLAB_U4  409600              // SLAB_U16/8

typedef unsigned short u16;
typedef unsigned int u32;
typedef float f32x16 __attribute__((ext_vector_type(16)));
typedef __bf16 bf16x8 __attribute__((ext_vector_type(8)));

__device__ __forceinline__ int refl(int p){ return p<0 ? -p : (p>=NXY ? 2*(NXY-1)-p : p); }
__device__ __forceinline__ u16 bf16_rn(float x){
    u32 u = __float_as_uint(x);
    return (u16)((u + 0x7fffu + ((u>>16)&1u)) >> 16);
}
__device__ __forceinline__ float bf16_f(u16 h){ return __uint_as_float(((u32)h)<<16); }
__device__ __forceinline__ bf16x8 as_bf(uint4 v){ return __builtin_bit_cast(bf16x8, v); }
__device__ __forceinline__ void glds16(const uint4* g, uint4* l){
    __builtin_amdgcn_global_load_lds(
        (const __attribute__((address_space(1))) u32*)g,
        (__attribute__((address_space(3))) u32*)l, 16, 0, 0);
}

// ---- pack weights: chunk c = icb*9+tap (8192 B): [hl 2][MT 4][lane 64][8 u16] -------------------
__global__ void pack_w_kernel(const float* __restrict__ wr, const float* __restrict__ wi,
                              u16* __restrict__ Ap)
{
    const int c = blockIdx.x;                 // 0..71
    const int icb = c/9, tap = c - icb*9;
    const int t = threadIdx.x;
    const int lane = t & 63, MT = t >> 6;
    const int row = lane & 31;
    const int oc = MT*16 + (row & 15);
    const int ri_out = row >> 4;
    const int kh = lane >> 5;
    #pragma unroll
    for (int j = 0; j < 8; ++j){
        int ic = icb*8 + kh*4 + (j>>1);
        int ri = j & 1;
        float wrv = wr[(oc*64+ic)*9 + tap];
        float wiv = wi[(oc*64+ic)*9 + tap];
        float val = (ri_out==0) ? (ri ? -wiv : wrv) : (ri ? wrv : wiv);
        u16 h = bf16_rn(val);
        Ap[(size_t)c*4096 + ((0*4 + MT)*64 + lane)*8 + j] = h;
        Ap[(size_t)c*4096 + ((1*4 + MT)*64 + lane)*8 + j] = bf16_rn(val - bf16_f(h));
    }
}

// ---- pack iter ALL t into B-slab layout: [icb 8][px][2 uint4] hi + lo slab ----------------------
__global__ __launch_bounds__(256) void pack_iter_kernel(const float* __restrict__ it_r,
        const float* __restrict__ it_i, u16* __restrict__ Pit)
{
    __shared__ u32 smh[8192], sml[8192];
    const int t = blockIdx.y;
    const int tid = threadIdx.x;
    const int pxl = tid & 127, half = tid >> 7;
    const int px0 = blockIdx.x * 128;
    const int px = px0 + pxl;
    #pragma unroll 4
    for (int i = 0; i < 32; ++i){
        int ic = half*32 + i;
        float r  = it_r[((size_t)ic*NT + t)*SP + px];
        float im = it_i[((size_t)ic*NT + t)*SP + px];
        u16 rh = bf16_rn(r),  ih = bf16_rn(im);
        u16 rl = bf16_rn(r - bf16_f(rh)), il = bf16_rn(im - bf16_f(ih));
        int wofs = pxl*64 + (ic ^ (pxl & 31));
        smh[wofs] = (u32)rh | ((u32)ih << 16);
        sml[wofs] = (u32)rl | ((u32)il << 16);
    }
    __syncthreads();
    u16* slab = Pit + (size_t)t * SLOT_U16;
    uint4* gdst = half ? ((uint4*)slab + SLAB_U4) : (uint4*)slab;
    const u32* sm = half ? sml : smh;
    #pragma unroll
    for (int icb = 0; icb < 8; ++icb)
        #pragma unroll
        for (int q = 0; q < 2; ++q){
            uint4 v;
            #pragma unroll
            for (int d = 0; d < 4; ++d)
                ((u32*)&v)[d] = sm[pxl*64 + ((icb*8 + q*4 + d) ^ (pxl & 31))];
            gdst[((size_t)icb*SP + px)*2 + q] = v;
        }
}

// ---- i2h: 2-channel input conv + ALL biases -> pre (float2 [t][64][SP]) -------------------------
__global__ __launch_bounds__(256) void i2h_kernel(
    const float* __restrict__ in_r, const float* __restrict__ in_i,
    const float* __restrict__ w2r,  const float* __restrict__ w2i,
    const float* __restrict__ b2r,  const float* __restrict__ b2i,
    const float* __restrict__ bihr, const float* __restrict__ bihi,
    const float* __restrict__ bhhr, const float* __restrict__ bhhi,
    float2* __restrict__ pre)
{
    const int t = blockIdx.z, oc0 = blockIdx.y*8;
    const int px = blockIdx.x*256 + threadIdx.x;
    const int x = px/NXY, y = px - x*NXY;
    int offs[9];
    #pragma unroll
    for (int dx=-1; dx<=1; ++dx)
        #pragma unroll
        for (int dy=-1; dy<=1; ++dy)
            offs[(dx+1)*3+(dy+1)] = refl(x+dx)*NXY + refl(y+dy);
    float xr[2][9], xi[2][9];
    #pragma unroll
    for (int ic=0; ic<2; ++ic)
        #pragma unroll
        for (int k=0; k<9; ++k){
            xr[ic][k] = in_r[((size_t)ic*NT+t)*SP + offs[k]];
            xi[ic][k] = in_i[((size_t)ic*NT+t)*SP + offs[k]];
        }
    #pragma unroll
    for (int o=0; o<8; ++o){
        int oc = oc0+o;
        float ar = b2r[oc]+bihr[oc]+bhhr[oc];
        float ai = b2i[oc]+bihi[oc]+bhhi[oc];
        #pragma unroll
        for (int ic=0; ic<2; ++ic)
            #pragma unroll
            for (int k=0; k<9; ++k){
                float wr = w2r[(oc*2+ic)*9+k], wi = w2i[(oc*2+ic)*9+k];
                ar = fmaf(xr[ic][k], wr, ar); ar = fmaf(-xi[ic][k], wi, ar);
                ai = fmaf(xr[ic][k], wi, ai); ai = fmaf( xi[ic][k], wr, ai);
            }
        pre[((size_t)t*64+oc)*SP + px] = make_float2(ar, ai);
    }
}

// ---- GEMM: 32x32x16, 4 waves, wave = M128 x 32px, A L2->regs (3-set), B halo LDS (1 bar/icb) ----
#define MF(a,b,c) __builtin_amdgcn_mfma_f32_32x32x16_bf16(a,b,c,0,0,0)

#define LOADA(SET, CN) { \
    const uint4* ap_ = A4 + (size_t)(CN)*512 + lane; \
    SET##0 = ap_[0];   SET##1 = ap_[64];  SET##2 = ap_[128]; SET##3 = ap_[192]; \
    SET##4 = ap_[256]; SET##5 = ap_[320]; SET##6 = ap_[384]; SET##7 = ap_[448]; }

#define TAPX(TAP, CUR, NXT, DX, DY) { \
    { int cn_ = cbase + (TAP) + 2; if (cn_ < 72) LOADA(NXT, cn_) } \
    if ((TAP)==0 && icb < 7){ \
        const uint4* bsrc_ = Bh4 + (size_t)(icb+1)*51200; \
        glds16(bsrc_ + sB0, Bs + obuf + tid); \
        glds16(bsrc_ + sB1, Bs + obuf + 256 + tid); \
        glds16(bsrc_ + sB2, Bs + obuf + 512 + tid); } \
    const int hx_ = rowb + (DX); const int hy_ = c + 1 + (DY); \
    const int bq_ = bufb + ((hx_*18 + hy_) << 2); \
    const int sl_ = (kh + (hy_>>1) + ((hx_&1)<<1)) & 3; \
    uint4 RBH = Bs[bq_ + sl_]; \
    uint4 RBL = Bs[bq_ + ((sl_+2)&3)]; \
    bf16x8 BH = as_bf(RBH), BL = as_bf(RBL); \
    __builtin_amdgcn_s_setprio(1); \
    acc0 = MF(as_bf(CUR##0), BH, acc0); acc1 = MF(as_bf(CUR##1), BH, acc1); \
    acc2 = MF(as_bf(CUR##2), BH, acc2); acc3 = MF(as_bf(CUR##3), BH, acc3); \
    acc0 = MF(as_bf(CUR##0), BL, acc0); acc1 = MF(as_bf(CUR##1), BL, acc1); \
    acc2 = MF(as_bf(CUR##2), BL, acc2); acc3 = MF(as_bf(CUR##3), BL, acc3); \
    acc0 = MF(as_bf(CUR##4), BH, acc0); acc1 = MF(as_bf(CUR##5), BH, acc1); \
    acc2 = MF(as_bf(CUR##6), BH, acc2); acc3 = MF(as_bf(CUR##7), BH, acc3); \
    __builtin_amdgcn_s_setprio(0); }

#define EPI0(ACC, MT_)                                                         \
        _Pragma("unroll")                                                      \
        for (int g=0; g<2; ++g)                                                \
            _Pragma("unroll")                                                  \
            for (int d=0; d<4; ++d){                                           \
                int oc = (MT_)*16 + kh*4 + d + 8*g;                            \
                float2 p = pre_t[(size_t)oc*SP + px];                          \
                p.x += ACC[g*4+d];                                             \
                p.y += ACC[g*4+d+8];                                           \
                pre_t[(size_t)oc*SP + px] = p;                                 \
            }

#define EPI1(ACC, MT_)                                                         \
        _Pragma("unroll")                                                      \
        for (int g=0; g<2; ++g){                                               \
            uint4 hv, lv;                                                      \
            _Pragma("unroll")                                                  \
            for (int d=0; d<4; ++d){                                           \
                int oc = (MT_)*16 + kh*4 + d + 8*g;                            \
                float2 p = pre_t[(size_t)oc*SP + px];                          \
                float zr = p.x + ACC[g*4+d];                                   \
                float zi = p.y + ACC[g*4+d+8];                                 \
                float mag = sqrtf(zr*zr + zi*zi);                              \
                float sc = fmaxf(mag + modb[oc], 0.f) / (mag + 1e-8f);         \
                float hr = sc*zr, hm = sc*zi;                                  \
                size_t oidx = ((size_t)oc*NT + t)*SP + px;                     \
                if (first) out[oidx] = make_float2(hr, hm);                    \
                else { float2 o2 = out[oidx]; out[oidx] = make_float2(o2.x+hr, o2.y+hm); } \
                u16 rh = bf16_rn(hr), ih = bf16_rn(hm);                        \
                u16 rl = bf16_rn(hr - bf16_f(rh)), il = bf16_rn(hm - bf16_f(ih)); \
                ((u32*)&hv)[d] = (u32)rh | ((u32)ih<<16);                      \
                ((u32*)&lv)[d] = (u32)rl | ((u32)il<<16);                      \
            }                                                                  \
            size_t q = ((size_t)((MT_)*2+g)*SP + px)*2 + kh;                   \
            Ch4w[q] = hv; Cl4w[q] = lv;                                        \
        }

template<int MODE>
__global__ __launch_bounds__(256, 2) void gemm_kernel(
    const uint4* __restrict__ A4,      // [72 chunks][hl 2][MT 4][lane 64] uint4
    const u16* __restrict__ Bsrc,      // MODE0: pit (12 slots); MODE1: H (4 slots)
    float2* __restrict__ pre_b,
    float2* __restrict__ out,
    const float* __restrict__ modb,
    u16* __restrict__ Hw,
    int s)
{
    __shared__ uint4 Bs[1536];         // 2 x 12KB B halo buffers (720 used + pad)
    const int tid = threadIdx.x;
    const int lane = tid & 63, w = tid >> 6;
    const int l31 = lane & 31, kh = lane >> 5;
    const int c = l31 & 15, r = l31 >> 4;
    const int T = blockIdx.x;
    const int x0 = (T/10)*8, y0 = (T - (T/10)*10)*16;
    const int rowb = 2*w + r + 1;

    const uint4* Bh4; float2* pre_t;
    int dir = 0, t = 0;
    if constexpr (MODE==0){
        t = blockIdx.y;
        Bh4 = (const uint4*)(Bsrc + (size_t)t * SLOT_U16);
        pre_t = pre_b + (size_t)t * 64 * SP;
    } else {
        dir = blockIdx.y;
        int rp = (s+1) & 1;
        Bh4 = (const uint4*)(Bsrc + (size_t)(dir*2+rp) * SLOT_U16);
        t = dir ? (NT-1-s) : s;
        pre_t = pre_b + (size_t)t * 64 * SP;
    }

    f32x16 acc0 = (f32x16)0.f, acc1 = (f32x16)0.f;
    f32x16 acc2 = (f32x16)0.f, acc3 = (f32x16)0.f;

    const bool hasK = (MODE==0) || (s > 0);
    if (hasK){
        // per-thread glds source offsets (3 entries), minus the icb*51200 term
        int sB0, sB1, sB2;
        #pragma unroll
        for (int i = 0; i < 3; ++i){
            int e = i*256 + tid;
            int es = e >= 720 ? e - 720 : e;
            int p = es & 3, hq = es >> 2;
            int hx = hq/18, hy = hq - hx*18;
            int s4 = (p - (hy>>1) - 2*(hx&1)) & 3;
            int hl = s4 >> 1, khs = s4 & 1;
            int gx = refl(x0-1+hx), gy = refl(y0-1+hy);
            int v = hl*SLAB_U4 + (gx*NXY+gy)*2 + khs;
            if (i==0) sB0 = v; else if (i==1) sB1 = v; else sB2 = v;
        }

        uint4 aA0,aA1,aA2,aA3,aA4,aA5,aA6,aA7;
        uint4 aB0,aB1,aB2,aB3,aB4,aB5,aB6,aB7;
        uint4 aC0,aC1,aC2,aC3,aC4,aC5,aC6,aC7;

        LOADA(aA, 0)
        LOADA(aB, 1)
        glds16(Bh4 + sB0, Bs + tid);
        glds16(Bh4 + sB1, Bs + 256 + tid);
        glds16(Bh4 + sB2, Bs + 512 + tid);
        asm volatile("s_waitcnt vmcnt(0)" ::: "memory");
        __builtin_amdgcn_s_barrier();
        __builtin_amdgcn_sched_barrier(0);

        for (int icb = 0; icb < 8; ++icb){
            const int cbase = icb*9;
            const int bufb = (icb&1)*768;
            const int obuf = bufb ^ 768;
            TAPX(0, aA, aC, -1,-1)
            TAPX(1, aB, aA, -1, 0)
            TAPX(2, aC, aB, -1, 1)
            TAPX(3, aA, aC,  0,-1)
            TAPX(4, aB, aA,  0, 0)
            TAPX(5, aC, aB,  0, 1)
            TAPX(6, aA, aC,  1,-1)
            TAPX(7, aB, aA,  1, 0)
            TAPX(8, aC, aB,  1, 1)
            if (icb < 7){
                asm volatile("s_waitcnt vmcnt(16)" ::: "memory");
                __builtin_amdgcn_s_barrier();
                __builtin_amdgcn_sched_barrier(0);
            }
        }
    }

    const int px = (x0 + 2*w + r)*NXY + y0 + c;

    if constexpr (MODE==0){
        EPI0(acc0, 0)
        EPI0(acc1, 1)
        EPI0(acc2, 2)
        EPI0(acc3, 3)
    } else {
        u16* Chw = Hw + (size_t)(dir*2 + (s&1)) * SLOT_U16;
        uint4* Ch4w = (uint4*)Chw;
        uint4* Cl4w = Ch4w + SLAB_U4;
        const bool first = (s <= 5);
        EPI1(acc0, 0)
        EPI1(acc1, 1)
        EPI1(acc2, 2)
        EPI1(acc3, 3)
    }
}

extern "C" void kernel_launch(void* const* d_in, const int* in_sizes, int n_in,
                              void* d_out, int out_size, void* d_ws, size_t ws_size,
                              hipStream_t stream)
{
    const float* in_r  = (const float*)d_in[0];
    const float* in_i  = (const float*)d_in[1];
    const float* it_r  = (const float*)d_in[2];
    const float* it_i  = (const float*)d_in[3];
    const float* w2_r  = (const float*)d_in[4];
    const float* w2_i  = (const float*)d_in[5];
    const float* b2_r  = (const float*)d_in[6];
    const float* b2_i  = (const float*)d_in[7];
    const float* whh_r = (const float*)d_in[8];
    const float* whh_i = (const float*)d_in[9];
    const float* bhh_r = (const float*)d_in[10];
    const float* bhh_i = (const float*)d_in[11];
    const float* wih_r = (const float*)d_in[12];
    const float* wih_i = (const float*)d_in[13];
    const float* bih_r = (const float*)d_in[14];
    const float* bih_i = (const float*)d_in[15];
    const float* mod_b = (const float*)d_in[16];

    char* ws = (char*)d_ws;
    float2* pre = (float2*)ws;                             // 157,286,400 B
    u16*    H   = (u16*)(ws + 157286400);                  //  52,428,800 B (4 slots)
    u16*    Ahh = (u16*)(ws + 157286400 + 52428800);       //     589,824 B
    u16*    Aih = H + 2*SLOT_U16;                          // overlaps H slots 2,3 (dead until MODE1 s=0)
    u16*    Pit = (u16*)d_out;                             // 12 slots = 157,286,400 B (dead before out-writes)
    float2* out = (float2*)d_out;

    pack_w_kernel<<<72, 256, 0, stream>>>(whh_r, whh_i, Ahh);
    pack_w_kernel<<<72, 256, 0, stream>>>(wih_r, wih_i, Aih);
    pack_iter_kernel<<<dim3(200,12), 256, 0, stream>>>(it_r, it_i, Pit);
    i2h_kernel<<<dim3(100,8,12), 256, 0, stream>>>(in_r, in_i, w2_r, w2_i,
        b2_r, b2_i, bih_r, bih_i, bhh_r, bhh_i, pre);
    gemm_kernel<0><<<dim3(200,12), 256, 0, stream>>>((const uint4*)Aih, Pit,
        pre, nullptr, nullptr, nullptr, 0);
    for (int s = 0; s < NT; ++s)
        gemm_kernel<1><<<dim3(200,2), 256, 0, stream>>>((const uint4*)Ahh, H,
            pre, out, mod_b, H, s);
}

// Round 11
// 1405.530 us; speedup vs baseline: 1.0335x; 1.0335x over previous
//
#include <hip/hip_runtime.h>

#define NXY 160
#define NT 12
#define SP 25600
#define SLOT_U16 3276800ull          // u16 per bf16 activation slot: 8 icb * SP * 16
#define ICB_U4   51200               // uint4 stride per icb within a slot

typedef unsigned short u16;
typedef unsigned int u32;
typedef float f32x16 __attribute__((ext_vector_type(16)));
typedef __bf16 bf16x8 __attribute__((ext_vector_type(8)));

__device__ __forceinline__ int refl(int p){ return p<0 ? -p : (p>=NXY ? 2*(NXY-1)-p : p); }
__device__ __forceinline__ u16 bf16_rn(float x){
    u32 u = __float_as_uint(x);
    return (u16)((u + 0x7fffu + ((u>>16)&1u)) >> 16);
}
__device__ __forceinline__ float bf16_f(u16 h){ return __uint_as_float(((u32)h)<<16); }
__device__ __forceinline__ bf16x8 as_bf(uint4 v){ return __builtin_bit_cast(bf16x8, v); }
__device__ __forceinline__ void glds16(const uint4* g, uint4* l){
    __builtin_amdgcn_global_load_lds(
        (const __attribute__((address_space(1))) u32*)g,
        (__attribute__((address_space(3))) u32*)l, 16, 0, 0);
}

// ---- pack weights: chunk c = icb*9+tap (8192 B): [mgrp 2][hl 2][MTw 2][lane 64] uint4 -----------
// A-frag row = lane&31: oc = MT*16 + (row&15), ri_out = row>>4; k = (lane>>5)*8+j:
// ic = icb*8 + (lane>>5)*4 + (j>>1), ri = j&1. real-out: ri0->wr, ri1->-wi; imag-out: ri0->wi, ri1->wr.
__global__ void pack_w_kernel(const float* __restrict__ wr, const float* __restrict__ wi,
                              u16* __restrict__ Ap)
{
    const int c = blockIdx.x;                 // 0..71
    const int icb = c/9, tap = c - icb*9;
    const int tid = threadIdx.x;
    #pragma unroll
    for (int i = 0; i < 2; ++i){
        int e = i*256 + tid;                  // 0..511
        int mgrp = e>>8, hl = (e>>7)&1, MTw = (e>>6)&1, lane = e&63;
        int MT = mgrp*2 + MTw;
        int row = lane & 31;
        int oc = MT*16 + (row & 15);
        int rio = row >> 4;
        int kh = lane >> 5;
        #pragma unroll
        for (int j = 0; j < 8; ++j){
            int ic = icb*8 + kh*4 + (j>>1);
            int ri = j & 1;
            float wrv = wr[(oc*64+ic)*9 + tap];
            float wiv = wi[(oc*64+ic)*9 + tap];
            float val = (rio==0) ? (ri ? -wiv : wrv) : (ri ? wrv : wiv);
            u16 h = bf16_rn(val);
            Ap[(size_t)c*4096 + e*8 + j] = hl ? bf16_rn(val - bf16_f(h)) : h;
        }
    }
}

// ---- pack iter ALL t into bf16 slab: [icb 8][px][16 u16] ---------------------------------------
__global__ __launch_bounds__(256) void pack_iter_kernel(const float* __restrict__ it_r,
        const float* __restrict__ it_i, u16* __restrict__ Pit)
{
    __shared__ u32 sm[8192];
    const int t = blockIdx.y;
    const int tid = threadIdx.x;
    const int pxl = tid & 127, half = tid >> 7;
    const int px = blockIdx.x * 128 + pxl;
    #pragma unroll 4
    for (int i = 0; i < 32; ++i){
        int ic = half*32 + i;
        float r  = it_r[((size_t)ic*NT + t)*SP + px];
        float im = it_i[((size_t)ic*NT + t)*SP + px];
        sm[pxl*64 + (ic ^ (pxl & 31))] = (u32)bf16_rn(r) | ((u32)bf16_rn(im) << 16);
    }
    __syncthreads();
    uint4* gdst = (uint4*)(Pit + (size_t)t * SLOT_U16);
    #pragma unroll
    for (int icbq = 0; icbq < 4; ++icbq){
        int icb = half*4 + icbq;
        #pragma unroll
        for (int q = 0; q < 2; ++q){
            uint4 v;
            #pragma unroll
            for (int d = 0; d < 4; ++d)
                ((u32*)&v)[d] = sm[pxl*64 + ((icb*8 + q*4 + d) ^ (pxl & 31))];
            gdst[((size_t)icb*SP + px)*2 + q] = v;
        }
    }
}

// ---- i2h: 2-channel input conv + ALL biases -> pre (float2 [t][64][SP]) -------------------------
__global__ __launch_bounds__(256) void i2h_kernel(
    const float* __restrict__ in_r, const float* __restrict__ in_i,
    const float* __restrict__ w2r,  const float* __restrict__ w2i,
    const float* __restrict__ b2r,  const float* __restrict__ b2i,
    const float* __restrict__ bihr, const float* __restrict__ bihi,
    const float* __restrict__ bhhr, const float* __restrict__ bhhi,
    float2* __restrict__ pre)
{
    const int t = blockIdx.z, oc0 = blockIdx.y*8;
    const int px = blockIdx.x*256 + threadIdx.x;
    const int x = px/NXY, y = px - x*NXY;
    int offs[9];
    #pragma unroll
    for (int dx=-1; dx<=1; ++dx)
        #pragma unroll
        for (int dy=-1; dy<=1; ++dy)
            offs[(dx+1)*3+(dy+1)] = refl(x+dx)*NXY + refl(y+dy);
    float xr[2][9], xi[2][9];
    #pragma unroll
    for (int ic=0; ic<2; ++ic)
        #pragma unroll
        for (int k=0; k<9; ++k){
            xr[ic][k] = in_r[((size_t)ic*NT+t)*SP + offs[k]];
            xi[ic][k] = in_i[((size_t)ic*NT+t)*SP + offs[k]];
        }
    #pragma unroll
    for (int o=0; o<8; ++o){
        int oc = oc0+o;
        float ar = b2r[oc]+bihr[oc]+bhhr[oc];
        float ai = b2i[oc]+bihi[oc]+bhhi[oc];
        #pragma unroll
        for (int ic=0; ic<2; ++ic)
            #pragma unroll
            for (int k=0; k<9; ++k){
                float wr = w2r[(oc*2+ic)*9+k], wi = w2i[(oc*2+ic)*9+k];
                ar = fmaf(xr[ic][k], wr, ar); ar = fmaf(-xi[ic][k], wi, ar);
                ai = fmaf(xr[ic][k], wi, ai); ai = fmaf( xi[ic][k], wr, ai);
            }
        pre[((size_t)t*64+oc)*SP + px] = make_float2(ar, ai);
    }
}

// ---- GEMM: 32x32x16, 2 waves (mgrp), wave = M64 x 128px (nt=4), tile 4x32 -----------------------
// A: weights hi+lo, asm-pinned global->reg 3-set pipeline. B: bf16 halo in LDS, dbuf, 1 barrier/icb.
#define MF(a,b,c) __builtin_amdgcn_mfma_f32_32x32x16_bf16(a,b,c,0,0,0)

#define LOADA(D0,D1,D2,D3, CN) { \
    const char* ab_ = Abase + ((size_t)(CN) << 13); \
    asm volatile("global_load_dwordx4 %0, %4, %5\n\t" \
                 "global_load_dwordx4 %1, %4, %5 offset:1024\n\t" \
                 "global_load_dwordx4 %2, %4, %5 offset:2048\n\t" \
                 "global_load_dwordx4 %3, %4, %5 offset:3072" \
        : "=&v"(D0), "=&v"(D1), "=&v"(D2), "=&v"(D3) \
        : "v"(voff), "s"(ab_) : "memory"); }

#define TAP(T_, C0,C1,C2,C3, N0,N1,N2,N3, DX, DY, STA, STB, VM)                \
{                                                                              \
    if (STA) LOADA(N0,N1,N2,N3, cbase + (T_) + 2)                              \
    if (STB){                                                                  \
        __builtin_amdgcn_sched_barrier(0);                                     \
        const uint4* bsrc_ = Bh4 + (size_t)(icb+1)*ICB_U4;                     \
        glds16(bsrc_ + sB0, Bs + obuf + tid);                                  \
        glds16(bsrc_ + sB1, Bs + obuf + 128 + tid);                            \
        glds16(bsrc_ + sB2, Bs + obuf + 256 + tid);                            \
        glds16(bsrc_ + sB3, Bs + obuf + 384 + tid);                            \
        __builtin_amdgcn_sched_barrier(0);                                     \
    }                                                                          \
    asm volatile("s_waitcnt vmcnt(" VM ")" ::: "memory");                      \
    __builtin_amdgcn_sched_barrier(0);                                         \
    bf16x8 ah0_ = as_bf(C0), ah1_ = as_bf(C1);                                 \
    bf16x8 al0_ = as_bf(C2), al1_ = as_bf(C3);                                 \
    uint4 rb0_ = Bs[bufb + bB + (0+(DX))*34 + (DY)];                           \
    uint4 rb1_ = Bs[bufb + bB + (1+(DX))*34 + (DY)];                           \
    uint4 rb2_ = Bs[bufb + bB + (2+(DX))*34 + (DY)];                           \
    uint4 rb3_ = Bs[bufb + bB + (3+(DX))*34 + (DY)];                           \
    bf16x8 b0_ = as_bf(rb0_), b1_ = as_bf(rb1_), b2_ = as_bf(rb2_), b3_ = as_bf(rb3_); \
    __builtin_amdgcn_s_setprio(1);                                             \
    a00 = MF(ah0_, b0_, a00); a01 = MF(ah0_, b1_, a01);                        \
    a02 = MF(ah0_, b2_, a02); a03 = MF(ah0_, b3_, a03);                        \
    a10 = MF(ah1_, b0_, a10); a11 = MF(ah1_, b1_, a11);                        \
    a12 = MF(ah1_, b2_, a12); a13 = MF(ah1_, b3_, a13);                        \
    a00 = MF(al0_, b0_, a00); a01 = MF(al0_, b1_, a01);                        \
    a02 = MF(al0_, b2_, a02); a03 = MF(al0_, b3_, a03);                        \
    a10 = MF(al1_, b0_, a10); a11 = MF(al1_, b1_, a11);                        \
    a12 = MF(al1_, b2_, a12); a13 = MF(al1_, b3_, a13);                        \
    __builtin_amdgcn_s_setprio(0);                                             \
}

#define EPI0(ACC, MT_, PX_)                                                    \
        _Pragma("unroll")                                                      \
        for (int g=0; g<2; ++g)                                                \
            _Pragma("unroll")                                                  \
            for (int d=0; d<4; ++d){                                           \
                int oc = (MT_)*16 + 8*g + kh*4 + d;                            \
                float2 p = pre_t[(size_t)oc*SP + (PX_)];                       \
                p.x += ACC[g*4+d];                                             \
                p.y += ACC[(g+2)*4+d];                                         \
                pre_t[(size_t)oc*SP + (PX_)] = p;                              \
            }

#define EPI1(ACC, MT_, PX_)                                                    \
        _Pragma("unroll")                                                      \
        for (int g=0; g<2; ++g){                                               \
            uint4 hv;                                                          \
            _Pragma("unroll")                                                  \
            for (int d=0; d<4; ++d){                                           \
                int oc = (MT_)*16 + 8*g + kh*4 + d;                            \
                float2 p = pre_t[(size_t)oc*SP + (PX_)];                       \
                float zr = p.x + ACC[g*4+d];                                   \
                float zi = p.y + ACC[(g+2)*4+d];                               \
                float mag = sqrtf(zr*zr + zi*zi);                              \
                float sc = fmaxf(mag + modb[oc], 0.f) / (mag + 1e-8f);         \
                float hr = sc*zr, hm = sc*zi;                                  \
                size_t oidx = ((size_t)oc*NT + t)*SP + (PX_);                  \
                if (first) out[oidx] = make_float2(hr, hm);                    \
                else { float2 o2 = out[oidx]; out[oidx] = make_float2(o2.x+hr, o2.y+hm); } \
                ((u32*)&hv)[d] = (u32)bf16_rn(hr) | ((u32)bf16_rn(hm)<<16);    \
            }                                                                  \
            Ch4w[((size_t)((MT_)*2+g)*SP + (PX_))*2 + kh] = hv;                \
        }

template<int MODE>
__global__ __launch_bounds__(128, 2) void gemm_kernel(
    const char* __restrict__ Abase,    // [72 chunks][mgrp 2][hl 2][MTw 2][lane 64] uint4
    const u16* __restrict__ Bsrc,      // MODE0: Pit (12 slots); MODE1: H (4 slots)
    float2* __restrict__ pre_b,
    float2* __restrict__ out,
    const float* __restrict__ modb,
    u16* __restrict__ Hw,
    int s)
{
    __shared__ uint4 Bs[1024];         // 2 buf x 512 (408 used + pad) = 16 KB
    const int tid = threadIdx.x;
    const int lane = tid & 63, mgrp = tid >> 6;
    const int l31 = lane & 31, kh = lane >> 5;
    const int T = blockIdx.x;
    const int x0 = (T/5)*4, y0 = (T - (T/5)*5)*32;
    const int MTa = mgrp*2, MTb = mgrp*2 + 1;

    const uint4* Bh4; float2* pre_t;
    int dir = 0, t = 0;
    if constexpr (MODE==0){
        t = blockIdx.y;
        Bh4 = (const uint4*)(Bsrc + (size_t)t * SLOT_U16);
        pre_t = pre_b + (size_t)t * 64 * SP;
    } else {
        dir = blockIdx.y;
        int rp = (s+1) & 1;
        Bh4 = (const uint4*)(Bsrc + (size_t)(dir*2+rp) * SLOT_U16);
        t = dir ? (NT-1-s) : s;
        pre_t = pre_b + (size_t)t * 64 * SP;
    }

    f32x16 a00=(f32x16)0.f, a01=(f32x16)0.f, a02=(f32x16)0.f, a03=(f32x16)0.f;
    f32x16 a10=(f32x16)0.f, a11=(f32x16)0.f, a12=(f32x16)0.f, a13=(f32x16)0.f;

    const bool hasK = (MODE==0) || (s > 0);
    if (hasK){
        const u32 voff = mgrp*4096 + lane*16;
        const int bB = (kh*6 + 1)*34 + l31 + 1;
        int sB0, sB1, sB2, sB3;
        #pragma unroll
        for (int i = 0; i < 4; ++i){
            int e = i*128 + tid;
            int es = e > 407 ? 407 : e;
            int khs = es/204, rem = es - khs*204;
            int hx = rem/34, hy = rem - hx*34;
            int gx = refl(x0-1+hx), gy = refl(y0-1+hy);
            int v = (gx*NXY+gy)*2 + khs;
            if (i==0) sB0 = v; else if (i==1) sB1 = v; else if (i==2) sB2 = v; else sB3 = v;
        }

        uint4 s00,s01,s02,s03, s10,s11,s12,s13, s20,s21,s22,s23;
        LOADA(s00,s01,s02,s03, 0)
        LOADA(s10,s11,s12,s13, 1)
        glds16(Bh4 + sB0, Bs + tid);
        glds16(Bh4 + sB1, Bs + 128 + tid);
        glds16(Bh4 + sB2, Bs + 256 + tid);
        glds16(Bh4 + sB3, Bs + 384 + tid);
        asm volatile("s_waitcnt vmcnt(0)" ::: "memory");
        __builtin_amdgcn_s_barrier();
        __builtin_amdgcn_sched_barrier(0);

        for (int icb = 0; icb < 7; ++icb){
            const int cbase = icb*9;
            const int bufb = (icb&1)*512;
            const int obuf = bufb ^ 512;
            TAP(0, s00,s01,s02,s03, s20,s21,s22,s23, -1,-1, 1,0,"8")
            TAP(1, s10,s11,s12,s13, s00,s01,s02,s03, -1, 0, 1,0,"8")
            TAP(2, s20,s21,s22,s23, s10,s11,s12,s13, -1, 1, 1,0,"8")
            TAP(3, s00,s01,s02,s03, s20,s21,s22,s23,  0,-1, 1,0,"8")
            TAP(4, s10,s11,s12,s13, s00,s01,s02,s03,  0, 0, 1,0,"8")
            TAP(5, s20,s21,s22,s23, s10,s11,s12,s13,  0, 1, 1,0,"8")
            TAP(6, s00,s01,s02,s03, s20,s21,s22,s23,  1,-1, 1,0,"8")
            TAP(7, s10,s11,s12,s13, s00,s01,s02,s03,  1, 0, 1,1,"12")
            TAP(8, s20,s21,s22,s23, s10,s11,s12,s13,  1, 1, 1,0,"12")
            asm volatile("s_waitcnt vmcnt(4)" ::: "memory");
            __builtin_amdgcn_s_barrier();
            __builtin_amdgcn_sched_barrier(0);
        }
        {   // peeled icb = 7
            const int icb = 7; (void)icb;
            const int cbase = 63;
            const int bufb = 512;
            const int obuf = 0; (void)obuf;
            TAP(0, s00,s01,s02,s03, s20,s21,s22,s23, -1,-1, 1,0,"8")
            TAP(1, s10,s11,s12,s13, s00,s01,s02,s03, -1, 0, 1,0,"8")
            TAP(2, s20,s21,s22,s23, s10,s11,s12,s13, -1, 1, 1,0,"8")
            TAP(3, s00,s01,s02,s03, s20,s21,s22,s23,  0,-1, 1,0,"8")
            TAP(4, s10,s11,s12,s13, s00,s01,s02,s03,  0, 0, 1,0,"8")
            TAP(5, s20,s21,s22,s23, s10,s11,s12,s13,  0, 1, 1,0,"8")
            TAP(6, s00,s01,s02,s03, s20,s21,s22,s23,  1,-1, 1,0,"8")
            TAP(7, s10,s11,s12,s13, s00,s01,s02,s03,  1, 0, 0,0,"4")
            TAP(8, s20,s21,s22,s23, s10,s11,s12,s13,  1, 1, 0,0,"0")
        }
    }

    const int px0p = (x0+0)*NXY + y0 + l31;
    const int px1p = (x0+1)*NXY + y0 + l31;
    const int px2p = (x0+2)*NXY + y0 + l31;
    const int px3p = (x0+3)*NXY + y0 + l31;

    if constexpr (MODE==0){
        EPI0(a00, MTa, px0p) EPI0(a01, MTa, px1p) EPI0(a02, MTa, px2p) EPI0(a03, MTa, px3p)
        EPI0(a10, MTb, px0p) EPI0(a11, MTb, px1p) EPI0(a12, MTb, px2p) EPI0(a13, MTb, px3p)
    } else {
        uint4* Ch4w = (uint4*)(Hw + (size_t)(dir*2 + (s&1)) * SLOT_U16);
        const bool first = (s <= 5);
        EPI1(a00, MTa, px0p) EPI1(a01, MTa, px1p) EPI1(a02, MTa, px2p) EPI1(a03, MTa, px3p)
        EPI1(a10, MTb, px0p) EPI1(a11, MTb, px1p) EPI1(a12, MTb, px2p) EPI1(a13, MTb, px3p)
    }
}

extern "C" void kernel_launch(void* const* d_in, const int* in_sizes, int n_in,
                              void* d_out, int out_size, void* d_ws, size_t ws_size,
                              hipStream_t stream)
{
    const float* in_r  = (const float*)d_in[0];
    const float* in_i  = (const float*)d_in[1];
    const float* it_r  = (const float*)d_in[2];
    const float* it_i  = (const float*)d_in[3];
    const float* w2_r  = (const float*)d_in[4];
    const float* w2_i  = (const float*)d_in[5];
    const float* b2_r  = (const float*)d_in[6];
    const float* b2_i  = (const float*)d_in[7];
    const float* whh_r = (const float*)d_in[8];
    const float* whh_i = (const float*)d_in[9];
    const float* bhh_r = (const float*)d_in[10];
    const float* bhh_i = (const float*)d_in[11];
    const float* wih_r = (const float*)d_in[12];
    const float* wih_i = (const float*)d_in[13];
    const float* bih_r = (const float*)d_in[14];
    const float* bih_i = (const float*)d_in[15];
    const float* mod_b = (const float*)d_in[16];

    char* ws = (char*)d_ws;
    float2* pre = (float2*)ws;                             // 157,286,400 B
    u16*    H   = (u16*)(ws + 157286400);                  //  26,214,400 B (4 bf16 slots)
    u16*    Ahh = (u16*)(ws + 157286400 + 26214400);       //     589,824 B
    u16*    Aih = (u16*)(ws + 157286400 + 26214400 + 589824);
    u16*    Pit = (u16*)d_out;                             // 12 bf16 slots = 78.6 MB (dead before out-writes)
    float2* out = (float2*)d_out;

    pack_w_kernel<<<72, 256, 0, stream>>>(whh_r, whh_i, Ahh);
    pack_w_kernel<<<72, 256, 0, stream>>>(wih_r, wih_i, Aih);
    pack_iter_kernel<<<dim3(200,12), 256, 0, stream>>>(it_r, it_i, Pit);
    i2h_kernel<<<dim3(100,8,12), 256, 0, stream>>>(in_r, in_i, w2_r, w2_i,
        b2_r, b2_i, bih_r, bih_i, bhh_r, bhh_i, pre);
    gemm_kernel<0><<<dim3(200,12), 128, 0, stream>>>((const char*)Aih, Pit,
        pre, nullptr, nullptr, nullptr, 0);
    for (int s = 0; s < NT; ++s)
        gemm_kernel<1><<<dim3(200,2), 128, 0, stream>>>((const char*)Ahh, H,
            pre, out, mod_b, H, s);
}

// Round 13
// 1097.706 us; speedup vs baseline: 1.3234x; 1.2804x over previous
//
#include <hip/hip_runtime.h>

#define NXY 160
#define NT 12
#define SP 25600
#define SLOT_H 3276800ull            // u16 per H slot: 8 icb * SP * 16
#define SLOT_P 3686400ull            // u16 per Pit slot: 9 icb * SP * 16
#define ICB_BYTES 819200             // bytes per icb plane: SP*32

typedef unsigned short u16;
typedef unsigned int u32;
typedef float f32x16 __attribute__((ext_vector_type(16)));
typedef __bf16 bf16x8 __attribute__((ext_vector_type(8)));

__device__ __forceinline__ int refl(int p){ return p<0 ? -p : (p>=NXY ? 2*(NXY-1)-p : p); }
__device__ __forceinline__ u16 bf16_rn(float x){
    u32 u = __float_as_uint(x);
    return (u16)((u + 0x7fffu + ((u>>16)&1u)) >> 16);
}
__device__ __forceinline__ float bf16_f(u16 h){ return __uint_as_float(((u32)h)<<16); }
__device__ __forceinline__ bf16x8 as_bf(uint4 v){ return __builtin_bit_cast(bf16x8, v); }

// ---- pack weights (64-ic convs): chunk c = icb*9+tap (8KB): [mgrp 2][hl 2][MTw 2][lane 64] uint4
__global__ void pack_w_kernel(const float* __restrict__ wr, const float* __restrict__ wi,
                              u16* __restrict__ Ap)
{
    const int c = blockIdx.x;                 // 0..71
    const int icb = c/9, tap = c - icb*9;
    const int tid = threadIdx.x;
    #pragma unroll
    for (int i = 0; i < 2; ++i){
        int e = i*256 + tid;                  // 0..511
        int mgrp = e>>8, hl = (e>>7)&1, MTw = (e>>6)&1, lane = e&63;
        int MT = mgrp*2 + MTw;
        int row = lane & 31;
        int oc = MT*16 + (row & 15);
        int rio = row >> 4;
        int kh = lane >> 5;
        #pragma unroll
        for (int j = 0; j < 8; ++j){
            int ic = icb*8 + kh*4 + (j>>1);
            int ri = j & 1;
            float wrv = wr[(oc*64+ic)*9 + tap];
            float wiv = wi[(oc*64+ic)*9 + tap];
            float val = (rio==0) ? (ri ? -wiv : wrv) : (ri ? wrv : wiv);
            u16 h = bf16_rn(val);
            Ap[(size_t)c*4096 + e*8 + j] = hl ? bf16_rn(val - bf16_f(h)) : h;
        }
    }
}

// ---- pack input-conv weights into Aih chunks 72..80 (2 real channels, zero-padded to 8) + bias sums
__global__ void pack_w2_kernel(const float* __restrict__ w2r, const float* __restrict__ w2i,
    const float* __restrict__ b2r,  const float* __restrict__ b2i,
    const float* __restrict__ bihr, const float* __restrict__ bihi,
    const float* __restrict__ bhhr, const float* __restrict__ bhhi,
    u16* __restrict__ Aih, float2* __restrict__ bsum)
{
    if (blockIdx.x == 9){
        int oc = threadIdx.x;
        bsum[oc] = make_float2(b2r[oc]+bihr[oc]+bhhr[oc], b2i[oc]+bihi[oc]+bhhi[oc]);
        return;
    }
    const int tap = blockIdx.x;
    const int c = 72 + tap;
    #pragma unroll
    for (int i = 0; i < 8; ++i){
        int e = i*64 + threadIdx.x;
        int hl = (e>>7)&1, MTw = (e>>6)&1, lane = e&63;
        int MT = (e>>8)*2 + MTw;
        int row = lane & 31;
        int oc = MT*16 + (row & 15);
        int rio = row >> 4;
        int kh = lane >> 5;
        #pragma unroll
        for (int j = 0; j < 8; ++j){
            int vch = kh*4 + (j>>1);
            int ri = j & 1;
            float val = 0.f;
            if (vch < 2){
                float wrv = w2r[(oc*2+vch)*9 + tap];
                float wiv = w2i[(oc*2+vch)*9 + tap];
                val = (rio==0) ? (ri ? -wiv : wrv) : (ri ? wrv : wiv);
            }
            u16 h = bf16_rn(val);
            Aih[(size_t)c*4096 + e*8 + j] = hl ? bf16_rn(val - bf16_f(h)) : h;
        }
    }
}

// ---- pack iter + input into Pit bf16 slabs: [t][icb 9][px][16 u16] (icb 8 = input ch 0,1 + zeros)
__global__ __launch_bounds__(256) void pack_iter_kernel(const float* __restrict__ it_r,
        const float* __restrict__ it_i, const float* __restrict__ in_r,
        const float* __restrict__ in_i, u16* __restrict__ Pit)
{
    __shared__ u32 sm[8192];
    const int t = blockIdx.y;
    const int tid = threadIdx.x;
    const int pxl = tid & 127, half = tid >> 7;
    const int px = blockIdx.x * 128 + pxl;
    #pragma unroll 4
    for (int i = 0; i < 32; ++i){
        int ic = half*32 + i;
        float r  = it_r[((size_t)ic*NT + t)*SP + px];
        float im = it_i[((size_t)ic*NT + t)*SP + px];
        sm[pxl*64 + (ic ^ (pxl & 31))] = (u32)bf16_rn(r) | ((u32)bf16_rn(im) << 16);
    }
    __syncthreads();
    uint4* gdst = (uint4*)(Pit + (size_t)t * SLOT_P);
    #pragma unroll
    for (int icbq = 0; icbq < 4; ++icbq){
        int icb = half*4 + icbq;
        #pragma unroll
        for (int q = 0; q < 2; ++q){
            uint4 v;
            #pragma unroll
            for (int d = 0; d < 4; ++d)
                ((u32*)&v)[d] = sm[pxl*64 + ((icb*8 + q*4 + d) ^ (pxl & 31))];
            gdst[((size_t)icb*SP + px)*2 + q] = v;
        }
    }
    if (half == 0){
        float r0 = in_r[(size_t)(0*NT + t)*SP + px];
        float i0 = in_i[(size_t)(0*NT + t)*SP + px];
        float r1 = in_r[(size_t)(1*NT + t)*SP + px];
        float i1 = in_i[(size_t)(1*NT + t)*SP + px];
        uint4 q0, q1;
        ((u32*)&q0)[0] = (u32)bf16_rn(r0) | ((u32)bf16_rn(i0) << 16);
        ((u32*)&q0)[1] = (u32)bf16_rn(r1) | ((u32)bf16_rn(i1) << 16);
        ((u32*)&q0)[2] = 0; ((u32*)&q0)[3] = 0;
        ((u32*)&q1)[0] = 0; ((u32*)&q1)[1] = 0; ((u32*)&q1)[2] = 0; ((u32*)&q1)[3] = 0;
        gdst[((size_t)8*SP + px)*2 + 0] = q0;
        gdst[((size_t)8*SP + px)*2 + 1] = q1;
    }
}

// ---- GEMM: 32x32x16, ONE wave per block (M64 x 128px), zero LDS, zero barriers ------------------
// A and B both asm-pinned global->reg, 3-set rotation, 2-taps-ahead FIFO, vmcnt(16).
#define MF(a,b,c) __builtin_amdgcn_mfma_f32_32x32x16_bf16(a,b,c,0,0,0)

#define LOADA(D0,D1,D2,D3, G) { \
    const char* ab_ = Abase + ((size_t)(G) << 13); \
    asm volatile("global_load_dwordx4 %0, %4, %5\n\t" \
                 "global_load_dwordx4 %1, %4, %5 offset:1024\n\t" \
                 "global_load_dwordx4 %2, %4, %5 offset:2048\n\t" \
                 "global_load_dwordx4 %3, %4, %5 offset:3072" \
        : "=&v"(D0), "=&v"(D1), "=&v"(D2), "=&v"(D3) \
        : "v"(voffA), "s"(ab_) : "memory"); }

#define LOADB(D0,D1,D2,D3, XDX, YDY, BB) { \
    u32 v0_ = (u32)(xo0##XDX + yo##YDY); \
    u32 v1_ = (u32)(xo1##XDX + yo##YDY); \
    u32 v2_ = (u32)(xo2##XDX + yo##YDY); \
    u32 v3_ = (u32)(xo3##XDX + yo##YDY); \
    asm volatile("global_load_dwordx4 %0, %4, %8\n\t" \
                 "global_load_dwordx4 %1, %5, %8\n\t" \
                 "global_load_dwordx4 %2, %6, %8\n\t" \
                 "global_load_dwordx4 %3, %7, %8" \
        : "=&v"(D0), "=&v"(D1), "=&v"(D2), "=&v"(D3) \
        : "v"(v0_), "v"(v1_), "v"(v2_), "v"(v3_), "s"(BB) : "memory"); }

#define TAP(CA0,CA1,CA2,CA3, NA0,NA1,NA2,NA3, CB0,CB1,CB2,CB3, NB0,NB1,NB2,NB3, \
            G, XN, YN, BB, DO_, VM)                                              \
{                                                                                \
    if (DO_){ LOADA(NA0,NA1,NA2,NA3, G) LOADB(NB0,NB1,NB2,NB3, XN, YN, BB) }     \
    asm volatile("s_waitcnt vmcnt(" VM ")" ::: "memory");                        \
    __builtin_amdgcn_sched_barrier(0);                                           \
    bf16x8 ah0_=as_bf(CA0), ah1_=as_bf(CA1), al0_=as_bf(CA2), al1_=as_bf(CA3);   \
    bf16x8 b0_=as_bf(CB0), b1_=as_bf(CB1), b2_=as_bf(CB2), b3_=as_bf(CB3);       \
    __builtin_amdgcn_s_setprio(1);                                               \
    c00=MF(ah0_,b0_,c00); c01=MF(ah0_,b1_,c01); c02=MF(ah0_,b2_,c02); c03=MF(ah0_,b3_,c03); \
    c10=MF(ah1_,b0_,c10); c11=MF(ah1_,b1_,c11); c12=MF(ah1_,b2_,c12); c13=MF(ah1_,b3_,c13); \
    c00=MF(al0_,b0_,c00); c01=MF(al0_,b1_,c01); c02=MF(al0_,b2_,c02); c03=MF(al0_,b3_,c03); \
    c10=MF(al1_,b0_,c10); c11=MF(al1_,b1_,c11); c12=MF(al1_,b2_,c12); c13=MF(al1_,b3_,c13); \
    __builtin_amdgcn_s_setprio(0);                                               \
}

#define NINE_TAPS(BBC, BBN, G, DO7, DO8, VM7, VM8)                                          \
    TAP(w00,w01,w02,w03, w20,w21,w22,w23, b00,b01,b02,b03, b20,b21,b22,b23, (G)+2, m,p, BBC, 1, "16") \
    TAP(w10,w11,w12,w13, w00,w01,w02,w03, b10,b11,b12,b13, b00,b01,b02,b03, (G)+3, z,m, BBC, 1, "16") \
    TAP(w20,w21,w22,w23, w10,w11,w12,w13, b20,b21,b22,b23, b10,b11,b12,b13, (G)+4, z,z, BBC, 1, "16") \
    TAP(w00,w01,w02,w03, w20,w21,w22,w23, b00,b01,b02,b03, b20,b21,b22,b23, (G)+5, z,p, BBC, 1, "16") \
    TAP(w10,w11,w12,w13, w00,w01,w02,w03, b10,b11,b12,b13, b00,b01,b02,b03, (G)+6, p,m, BBC, 1, "16") \
    TAP(w20,w21,w22,w23, w10,w11,w12,w13, b20,b21,b22,b23, b10,b11,b12,b13, (G)+7, p,z, BBC, 1, "16") \
    TAP(w00,w01,w02,w03, w20,w21,w22,w23, b00,b01,b02,b03, b20,b21,b22,b23, (G)+8, p,p, BBC, 1, "16") \
    TAP(w10,w11,w12,w13, w00,w01,w02,w03, b10,b11,b12,b13, b00,b01,b02,b03, (G)+9, m,m, BBN, DO7, VM7) \
    TAP(w20,w21,w22,w23, w10,w11,w12,w13, b20,b21,b22,b23, b10,b11,b12,b13, (G)+10, m,z, BBN, DO8, VM8)

template<int MODE>
__global__ __launch_bounds__(64, 1) void gemm_kernel(
    const char* __restrict__ Abase,    // MODE0: 81 chunks; MODE1: 72 chunks
    const u16* __restrict__ Bsrc,      // MODE0: Pit (12 slots, 9 icb); MODE1: H (4 slots, 8 icb)
    float2* __restrict__ pre_b,
    float2* __restrict__ out,
    const float* __restrict__ modb,
    const float2* __restrict__ bsum,
    u16* __restrict__ Hw,
    int s)
{
    constexpr int NI = (MODE==0) ? 9 : 8;
    const int lane = threadIdx.x;
    const int l31 = lane & 31, kh = lane >> 5;
    const int mgrp = blockIdx.y;
    const int T = blockIdx.x;
    const int x0 = (T/5)*4, y0 = (T - (T/5)*5)*32;
    const int MTa = mgrp*2, MTb = mgrp*2 + 1;

    const u16* Bh; float2* pre_t;
    int dir = 0, t = 0;
    if constexpr (MODE==0){
        t = blockIdx.z;
        Bh = Bsrc + (size_t)t * SLOT_P;
        pre_t = pre_b + (size_t)t * 64 * SP;
    } else {
        dir = blockIdx.z;
        int rp = (s+1) & 1;
        Bh = Bsrc + (size_t)(dir*2+rp) * SLOT_H;
        t = dir ? (NT-1-s) : s;
        pre_t = pre_b + (size_t)t * 64 * SP;
    }

    f32x16 c00=(f32x16)0.f, c01=(f32x16)0.f, c02=(f32x16)0.f, c03=(f32x16)0.f;
    f32x16 c10=(f32x16)0.f, c11=(f32x16)0.f, c12=(f32x16)0.f, c13=(f32x16)0.f;

    const bool hasK = (MODE==0) || (s > 0);
    if (hasK){
        const u32 voffA = mgrp*4096 + lane*16;
        const int yc = y0 + l31;
        const int yom = refl(yc-1)*32 + kh*16;
        const int yoz = yc*32 + kh*16;
        const int yop = refl(yc+1)*32 + kh*16;
        const int xo0m = refl(x0-1)*5120, xo0z = x0*5120,     xo0p = (x0+1)*5120;
        const int xo1m = x0*5120,         xo1z = (x0+1)*5120, xo1p = (x0+2)*5120;
        const int xo2m = (x0+1)*5120,     xo2z = (x0+2)*5120, xo2p = (x0+3)*5120;
        const int xo3m = (x0+2)*5120,     xo3z = (x0+3)*5120, xo3p = refl(x0+4)*5120;

        uint4 w00,w01,w02,w03, w10,w11,w12,w13, w20,w21,w22,w23;
        uint4 b00,b01,b02,b03, b10,b11,b12,b13, b20,b21,b22,b23;

        const char* bb = (const char*)Bh;
        LOADA(w00,w01,w02,w03, 0)
        LOADB(b00,b01,b02,b03, m, m, bb)
        LOADA(w10,w11,w12,w13, 1)
        LOADB(b10,b11,b12,b13, m, z, bb)

        for (int icb = 0; icb < NI-1; ++icb){
            const int g = icb*9;
            const char* bbn = bb + ICB_BYTES;
            NINE_TAPS(bb, bbn, g, 1, 1, "16", "16")
            bb = bbn;
        }
        {   // peeled last icb: taps 7,8 issue nothing; taper vmcnt
            const int g = (NI-1)*9;
            NINE_TAPS(bb, bb, g, 0, 0, "8", "0")
        }
    }

    const int pxr0 = (x0+0)*NXY + y0 + l31;
    const int pxr1 = (x0+1)*NXY + y0 + l31;
    const int pxr2 = (x0+2)*NXY + y0 + l31;
    const int pxr3 = (x0+3)*NXY + y0 + l31;

    if constexpr (MODE==0){
        #define EPI0(ACC, MT_, PX_)                                            \
            _Pragma("unroll")                                                  \
            for (int g=0; g<2; ++g)                                            \
                _Pragma("unroll")                                              \
                for (int d=0; d<4; ++d){                                       \
                    int oc = (MT_)*16 + 8*g + kh*4 + d;                        \
                    float2 bs = bsum[oc];                                      \
                    pre_t[(size_t)oc*SP + (PX_)] =                             \
                        make_float2(bs.x + ACC[g*4+d], bs.y + ACC[(g+2)*4+d]); \
                }
        EPI0(c00, MTa, pxr0) EPI0(c01, MTa, pxr1) EPI0(c02, MTa, pxr2) EPI0(c03, MTa, pxr3)
        EPI0(c10, MTb, pxr0) EPI0(c11, MTb, pxr1) EPI0(c12, MTb, pxr2) EPI0(c13, MTb, pxr3)
        #undef EPI0
    } else {
        uint4* Ch4w = (uint4*)(Hw + (size_t)(dir*2 + (s&1)) * SLOT_H);
        const bool first = (s <= 5);
        #define EPI1(ACC, MT_, PX_)                                            \
            _Pragma("unroll")                                                  \
            for (int g=0; g<2; ++g){                                           \
                uint4 hv;                                                      \
                _Pragma("unroll")                                              \
                for (int d=0; d<4; ++d){                                       \
                    int oc = (MT_)*16 + 8*g + kh*4 + d;                        \
                    float2 p = pre_t[(size_t)oc*SP + (PX_)];                   \
                    float zr = p.x + ACC[g*4+d];                               \
                    float zi = p.y + ACC[(g+2)*4+d];                           \
                    float mag = sqrtf(zr*zr + zi*zi);                          \
                    float sc = fmaxf(mag + modb[oc], 0.f) / (mag + 1e-8f);     \
                    float hr = sc*zr, hm = sc*zi;                              \
                    size_t oidx = ((size_t)oc*NT + t)*SP + (PX_);              \
                    if (first) out[oidx] = make_float2(hr, hm);                \
                    else { float2 o2 = out[oidx]; out[oidx] = make_float2(o2.x+hr, o2.y+hm); } \
                    ((u32*)&hv)[d] = (u32)bf16_rn(hr) | ((u32)bf16_rn(hm)<<16);\
                }                                                              \
                Ch4w[((size_t)((MT_)*2+g)*SP + (PX_))*2 + kh] = hv;            \
            }
        EPI1(c00, MTa, pxr0) EPI1(c01, MTa, pxr1) EPI1(c02, MTa, pxr2) EPI1(c03, MTa, pxr3)
        EPI1(c10, MTb, pxr0) EPI1(c11, MTb, pxr1) EPI1(c12, MTb, pxr2) EPI1(c13, MTb, pxr3)
        #undef EPI1
    }
}

extern "C" void kernel_launch(void* const* d_in, const int* in_sizes, int n_in,
                              void* d_out, int out_size, void* d_ws, size_t ws_size,
                              hipStream_t stream)
{
    const float* in_r  = (const float*)d_in[0];
    const float* in_i  = (const float*)d_in[1];
    const float* it_r  = (const float*)d_in[2];
    const float* it_i  = (const float*)d_in[3];
    const float* w2_r  = (const float*)d_in[4];
    const float* w2_i  = (const float*)d_in[5];
    const float* b2_r  = (const float*)d_in[6];
    const float* b2_i  = (const float*)d_in[7];
    const float* whh_r = (const float*)d_in[8];
    const float* whh_i = (const float*)d_in[9];
    const float* bhh_r = (const float*)d_in[10];
    const float* bhh_i = (const float*)d_in[11];
    const float* wih_r = (const float*)d_in[12];
    const float* wih_i = (const float*)d_in[13];
    const float* bih_r = (const float*)d_in[14];
    const float* bih_i = (const float*)d_in[15];
    const float* mod_b = (const float*)d_in[16];

    char* ws = (char*)d_ws;
    float2* pre = (float2*)ws;                             // 157,286,400 B
    u16*    H    = (u16*)(ws + 157286400);                 //  26,214,400 B (4 H slots)
    u16*    Ahh  = (u16*)(ws + 157286400 + 26214400);      //     589,824 B (72 chunks)
    u16*    Aih  = (u16*)(ws + 157286400 + 26214400 + 589824);   // 663,552 B (81 chunks)
    float2* bsum = (float2*)(ws + 157286400 + 26214400 + 589824 + 663552);  // 512 B
    u16*    Pit  = (u16*)d_out;                            // 12 slots x 9 icb = 88.5 MB (dead before out-writes)
    float2* out  = (float2*)d_out;

    pack_w_kernel<<<72, 256, 0, stream>>>(whh_r, whh_i, Ahh);
    pack_w_kernel<<<72, 256, 0, stream>>>(wih_r, wih_i, Aih);
    pack_w2_kernel<<<10, 64, 0, stream>>>(w2_r, w2_i, b2_r, b2_i, bih_r, bih_i,
        bhh_r, bhh_i, Aih, bsum);
    pack_iter_kernel<<<dim3(200,12), 256, 0, stream>>>(it_r, it_i, in_r, in_i, Pit);
    gemm_kernel<0><<<dim3(200,2,12), 64, 0, stream>>>((const char*)Aih, Pit,
        pre, nullptr, nullptr, bsum, nullptr, 0);
    for (int s = 0; s < NT; ++s)
        gemm_kernel<1><<<dim3(200,2,2), 64, 0, stream>>>((const char*)Ahh, H,
            pre, out, mod_b, nullptr, H, s);
}